// Round 5
// baseline (651.441 us; speedup 1.0000x reference)
//
#include <hip/hip_runtime.h>
#include <hip/hip_cooperative_groups.h>

namespace cg = cooperative_groups;

// GAT encoder, MI355X — round 5: single cooperative kernel (6 phases, 5 grid.sync).
// Algorithm identical to round 3 (passed, absmax 9.8e-4):
//  L1 (500 edges) -> <=500 special nodes; all others x1 = b1.
//  L2: plain nodes share h2=hb. Softmax shift m=e_plain(d): plain weight = 1.
//  out[d] = b2 + coef*hb + sum_spec w*(h2-hb); den via (exp-1 per special edge)
//  + (+1 per in-edge of special dst). Bucketed special-edge lists + per-dst chains.

#define LRELU(v) ((v) >= 0.0f ? (v) : 0.2f * (v))
#define EPSF 1e-16f
#define NB 128
#define BCAP 512

struct P {
    const float* x; const int* EI; int E, N;
    const float *W1, *a_src1, *a_dst1, *b1, *W2, *a_src2, *a_dst2, *b2;
    float* F; int* bcnt; int* idx_map; int* map2; float* s_spec; char* stat;
    float* x1acc; float* e1g; float* h2tab; float* as2tab; float* ad2tab;
    int* slw; int* nxt; float4* out;
};

__device__ __forceinline__ float wred_sum(float v) {
    for (int o = 32; o; o >>= 1) v += __shfl_xor(v, o);
    return v;
}
__device__ __forceinline__ int wred_min(int v) {
    for (int o = 32; o; o >>= 1) v = min(v, __shfl_xor(v, o));
    return v;
}

__device__ __forceinline__ void d_init(const P& p, int tid, int nth) {
    for (int i = tid; i < p.N; i += nth) {
        p.idx_map[i] = -1; p.map2[i] = -1; p.s_spec[i] = 0.f; p.stat[i] = 0;
    }
    for (int i = tid; i < 32768; i += nth) p.x1acc[i] = 0.f;
    for (int i = tid; i < NB * 16; i += nth) p.bcnt[i] = 0;
}

__device__ __forceinline__ void d_F(const P& p, int t) {   // one wave, t = lane
    float ws = 0.f, wd = 0.f, hb = 0.f;
    for (int l = 0; l < 64; ++l) { ws += p.W1[t*64+l]*p.a_src1[l]; wd += p.W1[t*64+l]*p.a_dst1[l]; }
    for (int k = 0; k < 64; ++k) hb += p.b1[k]*p.W2[k*64+t];
    p.F[t] = ws; p.F[64+t] = wd; p.F[128+t] = hb;
    float as = wred_sum(hb * p.a_src2[t]);
    float ad = wred_sum(hb * p.a_dst2[t]);
    if (t == 0) { p.F[192] = as; p.F[193] = ad; }
}

__device__ __forceinline__ void d_e1(const P& p, int w, int lane) {
    float ws = 0.f, wd = 0.f;   // recompute locally; no dep on F
    for (int l = 0; l < 64; ++l) { ws += p.W1[lane*64+l]*p.a_src1[l]; wd += p.W1[lane*64+l]*p.a_dst1[l]; }
    int s = p.EI[w], d = p.EI[p.E + w];
    float v = p.x[(long)s*64 + lane] * ws + p.x[(long)d*64 + lane] * wd;
    v = wred_sum(v);
    if (lane == 0) p.e1g[w] = LRELU(v);
}

__device__ __forceinline__ void d_l1bc(const P& p, int w, int lane) {
    int s = p.EI[w], d = p.EI[p.E + w];
    float myv = p.e1g[w];
    float sum = 0.f; int firstj = 1 << 30;
    #pragma unroll
    for (int r = 0; r < 8; ++r) {
        int j = r * 64 + lane;
        if (j < 500 && p.EI[p.E + j] == d) { sum += expf(p.e1g[j] - myv); firstj = min(firstj, j); }
    }
    sum = wred_sum(sum);
    firstj = wred_min(firstj);
    if (w == firstj && lane == 0) p.idx_map[d] = w;
    float wt = 1.0f / (sum + EPSF);
    float xs = p.x[(long)s*64 + lane];
    float h1l = 0.f;
    #pragma unroll
    for (int k = 0; k < 64; ++k) h1l = fmaf(__shfl(xs, k), p.W1[k*64 + lane], h1l);
    atomicAdd(&p.x1acc[firstj*64 + lane], wt * h1l);
}

__device__ __forceinline__ void d_l1d(const P& p, int w, int lane) {
    int d = p.EI[p.E + w];
    if (p.idx_map[d] != w) return;     // only the owning (first-occurrence) edge
    float x1 = p.x1acc[w*64 + lane] + p.b1[lane];
    float h2l = 0.f;
    #pragma unroll
    for (int k = 0; k < 64; ++k) h2l = fmaf(__shfl(x1, k), p.W2[k*64 + lane], h2l);
    p.h2tab[w*64 + lane] = h2l - p.F[128 + lane];   // store (h2 - hb)
    float as = wred_sum(h2l * p.a_src2[lane]);
    float ad = wred_sum(h2l * p.a_dst2[lane]);
    if (lane == 0) { p.as2tab[w] = as; p.ad2tab[w] = ad; }
}

__device__ __forceinline__ void d_specEdge(const P& p, long e, int s, int bkt,
                                           float asb, float adb) {
    int sl = p.idx_map[s];
    if (sl < 0) return;
    int d = p.EI[p.E + e];
    int jd = p.idx_map[d];
    float ad2v = (jd >= 0) ? p.ad2tab[jd] : adb;
    float md  = LRELU(asb + ad2v);
    float esp = LRELU(p.as2tab[sl] + ad2v);
    atomicAdd(&p.s_spec[d], expf(esp - md) - 1.0f);
    p.stat[d] = 2;
    int i = atomicAdd(&p.bcnt[bkt * 16], 1);       // 128 padded bucket counters
    if (i < BCAP) {
        int pos = bkt * BCAP + i;
        p.slw[pos] = sl;
        p.nxt[pos] = atomicExch(&p.map2[d], pos);
    }
}

__device__ __forceinline__ void d_scanA(const P& p, long q, float asb, float adb) {
    long base = 500 + q * 4;
    int bkt = (int)(q & (NB - 1));
    if (base + 3 < p.E) {
        int4 s4 = *(const int4*)(p.EI + base);
        d_specEdge(p, base + 0, s4.x, bkt, asb, adb);
        d_specEdge(p, base + 1, s4.y, bkt, asb, adb);
        d_specEdge(p, base + 2, s4.z, bkt, asb, adb);
        d_specEdge(p, base + 3, s4.w, bkt, asb, adb);
    } else {
        for (long e = base; e < p.E; ++e) d_specEdge(p, e, p.EI[e], bkt, asb, adb);
    }
}

__device__ __forceinline__ void d_dstEdge(const P& p, int d) {
    char st = p.stat[d];
    if (st == 0) p.stat[d] = 1;                     // benign race
    else if (st == 2) atomicAdd(&p.s_spec[d], 1.0f);
}

__device__ __forceinline__ void d_scanB(const P& p, long q) {
    long base = 500 + q * 4;
    if (base + 3 < p.E && ((p.E & 3) == 0)) {
        int4 d4 = *(const int4*)(p.EI + p.E + base);
        d_dstEdge(p, d4.x); d_dstEdge(p, d4.y); d_dstEdge(p, d4.z); d_dstEdge(p, d4.w);
    } else {
        for (long e = base; e < p.E; ++e) d_dstEdge(p, p.EI[p.E + e]);
    }
}

__device__ __forceinline__ void d_out(const P& p, long t, float asb, float adb) {
    int n = (int)(t >> 4), q = (int)(t & 15);
    char st = p.stat[n];
    float4 hb4 = ((const float4*)(p.F + 128))[q];
    float4 b24 = ((const float4*)p.b2)[q];
    float coef = (st != 0) ? 1.0f : 0.0f;
    float4 o;
    o.x = b24.x + coef * hb4.x; o.y = b24.y + coef * hb4.y;
    o.z = b24.z + coef * hb4.z; o.w = b24.w + coef * hb4.w;
    if (st == 2) {
        float den = p.s_spec[n] + EPSF;
        int jd = p.idx_map[n];
        float ad2v = (jd >= 0) ? p.ad2tab[jd] : adb;
        float md = LRELU(asb + ad2v);
        int pos = p.map2[n];
        while (pos >= 0) {
            int sl = p.slw[pos];
            float w = expf(LRELU(p.as2tab[sl] + ad2v) - md) / den;
            float4 h4 = ((const float4*)(p.h2tab + sl*64))[q];
            o.x = fmaf(w, h4.x, o.x); o.y = fmaf(w, h4.y, o.y);
            o.z = fmaf(w, h4.z, o.z); o.w = fmaf(w, h4.w, o.w);
            pos = p.nxt[pos];
        }
    }
    p.out[t] = o;
}

// ---------------- fused cooperative kernel ----------------
__global__ __launch_bounds__(256, 4) void fusedk(P p) {
    cg::grid_group gg = cg::this_grid();
    const int tid  = blockIdx.x * 256 + threadIdx.x;
    const int nth  = gridDim.x * 256;
    const int lane = threadIdx.x & 63;
    const int gw   = tid >> 6;

    d_init(p, tid, nth);
    if (gw < 500) d_e1(p, gw, lane);
    else if (gw == 500) d_F(p, lane);
    gg.sync();

    if (gw < 500) d_l1bc(p, gw, lane);
    gg.sync();

    if (gw < 500) d_l1d(p, gw, lane);
    gg.sync();

    const float asb = p.F[192], adb = p.F[193];
    const long G4 = ((long)p.E - 500 + 3) >> 2;
    for (long q = tid; q < G4; q += nth) d_scanA(p, q, asb, adb);
    gg.sync();

    for (long q = tid; q < G4; q += nth) d_scanB(p, q);
    gg.sync();

    const long M = (long)p.N * 16;
    for (long t = tid; t < M; t += nth) d_out(p, t, asb, adb);
}

// ---------------- fallback (non-cooperative) path ----------------
__global__ void k_prep(P p) {
    int tid = blockIdx.x * 256 + threadIdx.x;
    d_init(p, tid, gridDim.x * 256);
    int gw = tid >> 6, lane = threadIdx.x & 63;
    if (gw < 500) d_e1(p, gw, lane);
    else if (gw == 500) d_F(p, lane);
}
__global__ void k_l1bc(P p) {
    int gw = (blockIdx.x * 256 + threadIdx.x) >> 6;
    if (gw < 500) d_l1bc(p, gw, threadIdx.x & 63);
}
__global__ void k_l1d(P p) {
    int gw = (blockIdx.x * 256 + threadIdx.x) >> 6;
    if (gw < 500) d_l1d(p, gw, threadIdx.x & 63);
}
__global__ void k_scanA(P p) {
    int tid = blockIdx.x * 256 + threadIdx.x, nth = gridDim.x * 256;
    float asb = p.F[192], adb = p.F[193];
    long G4 = ((long)p.E - 500 + 3) >> 2;
    for (long q = tid; q < G4; q += nth) d_scanA(p, q, asb, adb);
}
__global__ void k_scanB(P p) {
    int tid = blockIdx.x * 256 + threadIdx.x, nth = gridDim.x * 256;
    long G4 = ((long)p.E - 500 + 3) >> 2;
    for (long q = tid; q < G4; q += nth) d_scanB(p, q);
}
__global__ void k_out(P p) {
    int tid = blockIdx.x * 256 + threadIdx.x, nth = gridDim.x * 256;
    float asb = p.F[192], adb = p.F[193];
    long M = (long)p.N * 16;
    for (long t = tid; t < M; t += nth) d_out(p, t, asb, adb);
}

extern "C" void kernel_launch(void* const* d_in, const int* in_sizes, int n_in,
                              void* d_out, int out_size, void* d_ws, size_t ws_size,
                              hipStream_t stream) {
    P p;
    p.x      = (const float*)d_in[0];
    p.EI     = (const int*)d_in[1];
    p.W1     = (const float*)d_in[2];
    p.a_src1 = (const float*)d_in[3];
    p.a_dst1 = (const float*)d_in[4];
    p.b1     = (const float*)d_in[5];
    p.W2     = (const float*)d_in[6];
    p.a_src2 = (const float*)d_in[7];
    p.a_dst2 = (const float*)d_in[8];
    p.b2     = (const float*)d_in[9];
    p.out    = (float4*)d_out;
    p.N = in_sizes[0] / 64;
    p.E = in_sizes[1] / 2;

    char* base = (char*)d_ws;
    p.F       = (float*)base;                         // 256 f
    p.bcnt    = (int*)(base + 1024);                  // NB*16
    p.idx_map = p.bcnt + NB * 16;                     // N
    p.map2    = p.idx_map + p.N;                      // N
    p.s_spec  = (float*)(p.map2 + p.N);               // N
    p.stat    = (char*)(p.s_spec + p.N);              // N
    char* q   = p.stat + p.N;
    q = (char*)(((uintptr_t)q + 63) & ~(uintptr_t)63);
    p.e1g     = (float*)q;                            // 512
    p.x1acc   = p.e1g + 512;                          // 32768
    p.h2tab   = p.x1acc + 32768;                      // 32768
    p.as2tab  = p.h2tab + 32768;                      // 512
    p.ad2tab  = p.as2tab + 512;                       // 512
    p.slw     = (int*)(p.ad2tab + 512);               // NB*BCAP
    p.nxt     = p.slw + NB * BCAP;                    // NB*BCAP

    int dev = 0;
    hipError_t e0 = hipGetDevice(&dev);
    int numCU = 0;
    hipError_t e1 = hipDeviceGetAttribute(&numCU, hipDeviceAttributeMultiprocessorCount, dev);
    int maxB = 0;
    hipError_t e2 = hipOccupancyMaxActiveBlocksPerMultiprocessor(&maxB, fusedk, 256, 0);

    hipError_t err = hipErrorUnknown;
    if (e0 == hipSuccess && e1 == hipSuccess && e2 == hipSuccess && numCU > 0 && maxB > 0) {
        int blk = maxB < 4 ? maxB : 4;
        int grid = numCU * blk;
        if (grid > 1024) grid = 1024;
        if (grid >= 128) {   // phases 0-2 need >= 501 waves (126 blocks)
            void* args[] = { &p };
            err = hipLaunchCooperativeKernel(reinterpret_cast<const void*>(fusedk),
                                             dim3(grid), dim3(256), args, 0, stream);
        }
    }
    if (err != hipSuccess) {
        // fallback: identical math, 6 plain launches
        k_prep <<<512, 256, 0, stream>>>(p);
        k_l1bc <<<125, 256, 0, stream>>>(p);
        k_l1d  <<<125, 256, 0, stream>>>(p);
        k_scanA<<<1024, 256, 0, stream>>>(p);
        k_scanB<<<1024, 256, 0, stream>>>(p);
        k_out  <<<1024, 256, 0, stream>>>(p);
    }
}

// Round 6
// 73.690 us; speedup vs baseline: 8.8404x; 8.8404x over previous
//
#include <hip/hip_runtime.h>

// GAT encoder, MI355X — round 6: 4 plain kernels (3 gaps), LDS-hash membership,
// register-resident layer 1. Math identical to round 3 (passed, absmax 9.8e-4):
//  L1 (500 edges) -> <=500 special nodes (owners); all others x1 = b1.
//  L2: plain nodes share h2=hb. Softmax shift m=e_plain(d): plain weight = 1.
//  out[d] = b2 + coef*hb + sum_spec w*(h2-hb);  den(d) = s_spec[d] =
//  (exp(esp-md)-1 per special edge, K2) + (1 per in-edge of special dst, K3).

#define LRELU(v) ((v) >= 0.0f ? (v) : 0.2f * (v))
#define EPSF 1e-16f
#define NB 128
#define BCAP 512
#define HSZ 1024

struct P {
    const float* x; const int* EI; int E, N;
    const float *W1, *a_src1, *a_dst1, *b1, *W2, *a_src2, *a_dst2, *b2;
    float* F;        // F[128..191]=hb, F[192]=as_base, F[193]=ad_base
    int* bcnt;       // NB*16 padded bucket counters
    int* map2;       // N: chain head per dst (-1)
    float* s_spec;   // N: denominator accumulator
    float* adsp;     // N: ad2 value of special dsts (written by K2)
    char* flag;      // N: has >=1 in-edge
    int* pkey;       // 512: owner edge -> dst node id (else -1)
    float* as2tab; float* ad2tab; float* h2tab;   // slot = owner edge id (0..499)
    int* slw; int* nxt;                            // bucketed chain storage
    float4* out;
};

__device__ __forceinline__ float wred_sum(float v) {
    for (int o = 32; o; o >>= 1) v += __shfl_xor(v, o);
    return v;
}
__device__ __forceinline__ int wred_min(int v) {
    for (int o = 32; o; o >>= 1) v = min(v, __shfl_xor(v, o));
    return v;
}

// ---------------- K1: init + full layer 1 (125 blocks, 500 waves) ----------------
__global__ __launch_bounds__(256) void k1(P p) {
    const int tid = blockIdx.x * 256 + threadIdx.x;
    const int nth = 125 * 256;
    for (int i = tid; i < p.N; i += nth) { p.map2[i] = -1; p.s_spec[i] = 0.f; p.flag[i] = 0; }
    for (int i = tid; i < NB * 16; i += nth) p.bcnt[i] = 0;

    const int w = tid >> 6, lane = threadIdx.x & 63;
    if (w >= 500) return;

    // per-lane weight vectors (L2-hot recompute; no cross-wave deps)
    float wsl = 0.f, wdl = 0.f, hbl = 0.f;
    for (int l = 0; l < 64; ++l) {
        wsl += p.W1[lane * 64 + l] * p.a_src1[l];
        wdl += p.W1[lane * 64 + l] * p.a_dst1[l];
    }
    for (int k = 0; k < 64; ++k) hbl += p.b1[k] * p.W2[k * 64 + lane];

    if (w == 0) {   // publish hb / as_base / ad_base
        p.F[128 + lane] = hbl;
        float asb = wred_sum(hbl * p.a_src2[lane]);
        float adb = wred_sum(hbl * p.a_dst2[lane]);
        if (lane == 0) { p.F[192] = asb; p.F[193] = adb; }
    }

    const int d = p.EI[p.E + w];
    // owner = min edge index with this dst
    int firstj = 1 << 30;
    for (int r = 0; r < 8; ++r) {
        int j = r * 64 + lane;
        if (j < 500 && p.EI[p.E + j] == d) firstj = min(firstj, j);
    }
    firstj = wred_min(firstj);
    const bool owner = (firstj == w);
    if (lane == 0) p.pkey[w] = owner ? d : -1;
    if (!owner) return;

    const float dv = wred_sum(p.x[(long)d * 64 + lane] * wdl);
    float Ssum = 0.f, e1w = 0.f, x1l = 0.f;
    bool fm = true;
    for (int r = 0; r < 8; ++r) {
        int j = r * 64 + lane;
        bool m = (j < 500) && (p.EI[p.E + j] == d);
        unsigned long long mask = __ballot(m);
        while (mask) {
            int j0 = r * 64 + (int)__ffsll(mask) - 1;
            mask &= mask - 1;
            int sj = p.EI[j0];
            float xs = p.x[(long)sj * 64 + lane];
            float e1j = LRELU(wred_sum(xs * wsl) + dv);
            float ew;
            if (fm) { e1w = e1j; ew = 1.f; fm = false; }   // first match == w (shift anchor)
            else ew = expf(e1j - e1w);
            Ssum += ew;
            float h1l = 0.f;
            #pragma unroll
            for (int k = 0; k < 64; ++k) h1l = fmaf(__shfl(xs, k), p.W1[k * 64 + lane], h1l);
            x1l = fmaf(ew, h1l, x1l);
        }
    }
    float x1 = x1l / (Ssum + EPSF) + p.b1[lane];
    float h2l = 0.f;
    #pragma unroll
    for (int k = 0; k < 64; ++k) h2l = fmaf(__shfl(x1, k), p.W2[k * 64 + lane], h2l);
    p.h2tab[w * 64 + lane] = h2l - hbl;               // store (h2 - hb)
    float as = wred_sum(h2l * p.a_src2[lane]);
    float ad = wred_sum(h2l * p.a_dst2[lane]);
    if (lane == 0) { p.as2tab[w] = as; p.ad2tab[w] = ad; }
}

// ---------------- K2: src-column scan with LDS hash ----------------
__device__ __forceinline__ int hlookup(const int* hkey, const int* hval, int x) {
    unsigned idx = ((unsigned)x * 2654435761u) >> 22;
    while (true) {
        int k = hkey[idx];
        if (k == -1) return -1;
        if (k == x) return hval[idx];
        idx = (idx + 1) & (HSZ - 1);
    }
}

__device__ __forceinline__ void specEdge(const P& p, long e, int s, int bkt,
                                         float asb, float adb,
                                         const int* hkey, const int* hval) {
    int sl = hlookup(hkey, hval, s);
    if (sl < 0) return;
    int d = p.EI[p.E + e];
    int jd = hlookup(hkey, hval, d);
    float ad2v = (jd >= 0) ? p.ad2tab[jd] : adb;
    float md  = LRELU(asb + ad2v);
    float esp = LRELU(p.as2tab[sl] + ad2v);
    atomicAdd(&p.s_spec[d], expf(esp - md) - 1.0f);
    p.adsp[d] = ad2v;                               // same value from all writers
    int i = atomicAdd(&p.bcnt[bkt * 16], 1);
    if (i < BCAP) {
        int pos = bkt * BCAP + i;
        p.slw[pos] = sl;
        p.nxt[pos] = atomicExch(&p.map2[d], pos);
    }
}

__global__ __launch_bounds__(1024) void k2(P p) {
    __shared__ int hkey[HSZ];
    __shared__ int hval[HSZ];
    for (int i = threadIdx.x; i < HSZ; i += 1024) hkey[i] = -1;
    __syncthreads();
    if (threadIdx.x < 500) {
        int key = p.pkey[threadIdx.x];
        if (key >= 0) {
            unsigned idx = ((unsigned)key * 2654435761u) >> 22;
            while (true) {
                int old = atomicCAS(&hkey[idx], -1, key);
                if (old == -1) { hval[idx] = threadIdx.x; break; }
                idx = (idx + 1) & (HSZ - 1);
            }
        }
    }
    __syncthreads();
    const float asb = p.F[192], adb = p.F[193];
    long q = (long)blockIdx.x * 1024 + threadIdx.x;
    long base = 500 + q * 4;
    if (base >= p.E) return;
    int bkt = (int)(q & (NB - 1));
    if (base + 3 < p.E) {
        int4 s4 = *(const int4*)(p.EI + base);
        specEdge(p, base + 0, s4.x, bkt, asb, adb, hkey, hval);
        specEdge(p, base + 1, s4.y, bkt, asb, adb, hkey, hval);
        specEdge(p, base + 2, s4.z, bkt, asb, adb, hkey, hval);
        specEdge(p, base + 3, s4.w, bkt, asb, adb, hkey, hval);
    } else {
        for (long e = base; e < p.E; ++e) specEdge(p, e, p.EI[e], bkt, asb, adb, hkey, hval);
    }
}

// ---------------- K3: dst-column scan ----------------
__device__ __forceinline__ void dstEdge(const P& p, int d) {
    p.flag[d] = 1;                                   // benign race, plain store
    if (p.map2[d] >= 0) atomicAdd(&p.s_spec[d], 1.0f);
}

__global__ __launch_bounds__(1024) void k3(P p) {
    long q = (long)blockIdx.x * 1024 + threadIdx.x;
    long base = 500 + q * 4;
    if (base >= p.E) return;
    if (base + 3 < p.E) {
        int4 d4 = *(const int4*)(p.EI + p.E + base);
        dstEdge(p, d4.x); dstEdge(p, d4.y); dstEdge(p, d4.z); dstEdge(p, d4.w);
    } else {
        for (long e = base; e < p.E; ++e) dstEdge(p, p.EI[p.E + e]);
    }
}

// ---------------- K4: output writer (hash-free) ----------------
__global__ __launch_bounds__(256) void k4(P p) {
    long t = (long)blockIdx.x * 256 + threadIdx.x;
    if (t >= (long)p.N * 16) return;
    int n = (int)(t >> 4), qq = (int)(t & 15);
    float coef = p.flag[n] ? 1.0f : 0.0f;
    float4 hb4 = ((const float4*)(p.F + 128))[qq];
    float4 b24 = ((const float4*)p.b2)[qq];
    float4 o;
    o.x = b24.x + coef * hb4.x; o.y = b24.y + coef * hb4.y;
    o.z = b24.z + coef * hb4.z; o.w = b24.w + coef * hb4.w;
    int pos = p.map2[n];
    if (pos >= 0) {
        float den = p.s_spec[n] + EPSF;
        float ad2v = p.adsp[n];
        float md = LRELU(p.F[192] + ad2v);
        while (pos >= 0) {
            int sl = p.slw[pos];
            float w = expf(LRELU(p.as2tab[sl] + ad2v) - md) / den;
            float4 h4 = ((const float4*)(p.h2tab + sl * 64))[qq];
            o.x = fmaf(w, h4.x, o.x); o.y = fmaf(w, h4.y, o.y);
            o.z = fmaf(w, h4.z, o.z); o.w = fmaf(w, h4.w, o.w);
            pos = p.nxt[pos];
        }
    }
    p.out[t] = o;
}

extern "C" void kernel_launch(void* const* d_in, const int* in_sizes, int n_in,
                              void* d_out, int out_size, void* d_ws, size_t ws_size,
                              hipStream_t stream) {
    P p;
    p.x      = (const float*)d_in[0];
    p.EI     = (const int*)d_in[1];
    p.W1     = (const float*)d_in[2];
    p.a_src1 = (const float*)d_in[3];
    p.a_dst1 = (const float*)d_in[4];
    p.b1     = (const float*)d_in[5];
    p.W2     = (const float*)d_in[6];
    p.a_src2 = (const float*)d_in[7];
    p.a_dst2 = (const float*)d_in[8];
    p.b2     = (const float*)d_in[9];
    p.out    = (float4*)d_out;
    p.N = in_sizes[0] / 64;
    p.E = in_sizes[1] / 2;

    char* base = (char*)d_ws;
    p.F      = (float*)base;                          // 256 floats
    p.bcnt   = (int*)(base + 1024);                   // NB*16
    p.map2   = p.bcnt + NB * 16;                      // N
    p.s_spec = (float*)(p.map2 + p.N);                // N
    p.adsp   = p.s_spec + p.N;                        // N
    p.flag   = (char*)(p.adsp + p.N);                 // N bytes
    char* q  = p.flag + p.N;
    q = (char*)(((uintptr_t)q + 63) & ~(uintptr_t)63);
    p.pkey   = (int*)q;                               // 512
    p.as2tab = (float*)(p.pkey + 512);                // 512
    p.ad2tab = p.as2tab + 512;                        // 512
    p.h2tab  = p.ad2tab + 512;                        // 512*64
    p.slw    = (int*)(p.h2tab + 512 * 64);            // NB*BCAP
    p.nxt    = p.slw + NB * BCAP;                     // NB*BCAP

    long quads = ((long)p.E - 500 + 3) / 4;
    int scanBlocks = (int)((quads + 1023) / 1024);

    k1<<<125, 256, 0, stream>>>(p);
    k2<<<scanBlocks, 1024, 0, stream>>>(p);
    k3<<<scanBlocks, 1024, 0, stream>>>(p);
    k4<<<(int)(((long)p.N * 16 + 255) / 256), 256, 0, stream>>>(p);
}

// Round 7
// 65.131 us; speedup vs baseline: 10.0020x; 1.1314x over previous
//
#include <hip/hip_runtime.h>

// GAT encoder, MI355X — round 7: 4 kernels, all 256-thread blocks (R3-proven
// scan geometry) + fused init/layer-1 (R6-validated math) + LDS-hash membership.
//  L1 (500 edges) -> <=500 special nodes (owner edges); all others x1 = b1.
//  L2: plain nodes share h2=hb. Softmax shift m=e_plain(d): plain weight = 1.
//  out[d] = b2 + coef*hb + sum_spec w*(h2-hb); den(d) = s_spec[d] =
//  (exp(esp-md)-1 per special edge, K2) + (+1 per in-edge of special dst, K3).

#define LRELU(v) ((v) >= 0.0f ? (v) : 0.2f * (v))
#define EPSF 1e-16f
#define NB 128
#define BCAP 512
#define HSZ 1024

struct P {
    const float* x; const int* EI; int E, N;
    const float *W1, *a_src1, *a_dst1, *b1, *W2, *a_src2, *a_dst2, *b2;
    float* F;        // F[128..191]=hb, F[192]=as_base, F[193]=ad_base
    int* bcnt;       // NB*16 padded bucket counters
    int* map2;       // N: chain head per dst (-1)
    float* s_spec;   // N: denominator accumulator
    float* adsp;     // N: ad2 value of special dsts (written by K2)
    char* stat;      // N: 0=no in-edge, 1=plain in-edge, 2=special dst
    int* pkey;       // 512: owner edge -> dst node id (else -1)
    float* as2tab; float* ad2tab; float* h2tab;   // slot = owner edge id (0..499)
    int* slw; int* nxt;                            // bucketed chain storage
    float4* out;
    int initBlocks;
};

__device__ __forceinline__ float wred_sum(float v) {
    for (int o = 32; o; o >>= 1) v += __shfl_xor(v, o);
    return v;
}
__device__ __forceinline__ int wred_min(int v) {
    for (int o = 32; o; o >>= 1) v = min(v, __shfl_xor(v, o));
    return v;
}

// ---------------- K1: init + full layer 1 ----------------
__global__ __launch_bounds__(256) void k1(P p) {
    const int tid = blockIdx.x * 256 + threadIdx.x;
    const int nth = p.initBlocks * 256;
    for (int i = tid; i < p.N; i += nth) { p.map2[i] = -1; p.s_spec[i] = 0.f; p.stat[i] = 0; }
    for (int i = tid; i < NB * 16; i += nth) p.bcnt[i] = 0;

    const int w = tid >> 6, lane = threadIdx.x & 63;
    if (w >= 500) return;

    // per-lane weight vectors (L2-hot recompute; no cross-wave deps)
    float wsl = 0.f, wdl = 0.f, hbl = 0.f;
    for (int l = 0; l < 64; ++l) {
        wsl += p.W1[lane * 64 + l] * p.a_src1[l];
        wdl += p.W1[lane * 64 + l] * p.a_dst1[l];
    }
    for (int k = 0; k < 64; ++k) hbl += p.b1[k] * p.W2[k * 64 + lane];

    if (w == 0) {   // publish hb / as_base / ad_base
        p.F[128 + lane] = hbl;
        float asb = wred_sum(hbl * p.a_src2[lane]);
        float adb = wred_sum(hbl * p.a_dst2[lane]);
        if (lane == 0) { p.F[192] = asb; p.F[193] = adb; }
    }

    const int d = p.EI[p.E + w];
    int firstj = 1 << 30;                 // owner = min edge index with this dst
    for (int r = 0; r < 8; ++r) {
        int j = r * 64 + lane;
        if (j < 500 && p.EI[p.E + j] == d) firstj = min(firstj, j);
    }
    firstj = wred_min(firstj);
    const bool owner = (firstj == w);
    if (lane == 0) p.pkey[w] = owner ? d : -1;
    if (!owner) return;

    const float dv = wred_sum(p.x[(long)d * 64 + lane] * wdl);
    float Ssum = 0.f, e1w = 0.f, x1l = 0.f;
    bool fm = true;
    for (int r = 0; r < 8; ++r) {
        int j = r * 64 + lane;
        bool m = (j < 500) && (p.EI[p.E + j] == d);
        unsigned long long mask = __ballot(m);
        while (mask) {
            int j0 = r * 64 + (int)__ffsll(mask) - 1;
            mask &= mask - 1;
            int sj = p.EI[j0];
            float xs = p.x[(long)sj * 64 + lane];
            float e1j = LRELU(wred_sum(xs * wsl) + dv);
            float ew;
            if (fm) { e1w = e1j; ew = 1.f; fm = false; }   // shift anchor = own score
            else ew = expf(e1j - e1w);
            Ssum += ew;
            float h1l = 0.f;
            #pragma unroll
            for (int k = 0; k < 64; ++k) h1l = fmaf(__shfl(xs, k), p.W1[k * 64 + lane], h1l);
            x1l = fmaf(ew, h1l, x1l);
        }
    }
    float x1 = x1l / (Ssum + EPSF) + p.b1[lane];
    float h2l = 0.f;
    #pragma unroll
    for (int k = 0; k < 64; ++k) h2l = fmaf(__shfl(x1, k), p.W2[k * 64 + lane], h2l);
    p.h2tab[w * 64 + lane] = h2l - hbl;               // store (h2 - hb)
    float as = wred_sum(h2l * p.a_src2[lane]);
    float ad = wred_sum(h2l * p.a_dst2[lane]);
    if (lane == 0) { p.as2tab[w] = as; p.ad2tab[w] = ad; }
}

// ---------------- K2: src-column scan (256-thr blocks, LDS hash) ----------------
__device__ __forceinline__ int hlookup(const int* hkey, const int* hval, int x) {
    unsigned idx = ((unsigned)x * 2654435761u) >> 22;
    while (true) {
        int k = hkey[idx];
        if (k == -1) return -1;
        if (k == x) return hval[idx];
        idx = (idx + 1) & (HSZ - 1);
    }
}

__device__ __forceinline__ void specEdge(const P& p, long e, int s, int bkt,
                                         float asb, float adb,
                                         const int* hkey, const int* hval) {
    int sl = hlookup(hkey, hval, s);
    if (sl < 0) return;
    int d = p.EI[p.E + e];
    int jd = hlookup(hkey, hval, d);
    float ad2v = (jd >= 0) ? p.ad2tab[jd] : adb;
    float md  = LRELU(asb + ad2v);
    float esp = LRELU(p.as2tab[sl] + ad2v);
    atomicAdd(&p.s_spec[d], expf(esp - md) - 1.0f);
    p.stat[d] = 2;                                   // overwrites 0/1; K3 sees 2
    p.adsp[d] = ad2v;                                // same value from all writers
    int i = atomicAdd(&p.bcnt[bkt * 16], 1);
    if (i < BCAP) {
        int pos = bkt * BCAP + i;
        p.slw[pos] = sl;
        p.nxt[pos] = atomicExch(&p.map2[d], pos);
    }
}

__global__ __launch_bounds__(256) void k2(P p) {
    __shared__ int hkey[HSZ];
    __shared__ int hval[HSZ];
    for (int i = threadIdx.x; i < HSZ; i += 256) hkey[i] = -1;
    __syncthreads();
    for (int i = threadIdx.x; i < 500; i += 256) {
        int key = p.pkey[i];
        if (key >= 0) {
            unsigned idx = ((unsigned)key * 2654435761u) >> 22;
            while (true) {
                int old = atomicCAS(&hkey[idx], -1, key);
                if (old == -1) { hval[idx] = i; break; }
                idx = (idx + 1) & (HSZ - 1);
            }
        }
    }
    __syncthreads();
    const float asb = p.F[192], adb = p.F[193];
    long q = (long)blockIdx.x * 256 + threadIdx.x;
    long base = 500 + q * 4;
    if (base >= p.E) return;
    int bkt = (int)(q & (NB - 1));
    if (base + 3 < p.E) {
        int4 s4 = *(const int4*)(p.EI + base);
        specEdge(p, base + 0, s4.x, bkt, asb, adb, hkey, hval);
        specEdge(p, base + 1, s4.y, bkt, asb, adb, hkey, hval);
        specEdge(p, base + 2, s4.z, bkt, asb, adb, hkey, hval);
        specEdge(p, base + 3, s4.w, bkt, asb, adb, hkey, hval);
    } else {
        for (long e = base; e < p.E; ++e) specEdge(p, e, p.EI[e], bkt, asb, adb, hkey, hval);
    }
}

// ---------------- K3: dst-column scan (256-thr blocks, char stat) ----------------
__device__ __forceinline__ void dstEdge(const P& p, int d) {
    char st = p.stat[d];
    if (st == 0) p.stat[d] = 1;                      // benign race
    else if (st == 2) atomicAdd(&p.s_spec[d], 1.0f);
}

__global__ __launch_bounds__(256) void k3(P p) {
    long q = (long)blockIdx.x * 256 + threadIdx.x;
    long base = 500 + q * 4;
    if (base >= p.E) return;
    if (base + 3 < p.E) {
        int4 d4 = *(const int4*)(p.EI + p.E + base);
        dstEdge(p, d4.x); dstEdge(p, d4.y); dstEdge(p, d4.z); dstEdge(p, d4.w);
    } else {
        for (long e = base; e < p.E; ++e) dstEdge(p, p.EI[p.E + e]);
    }
}

// ---------------- K4: output writer ----------------
__global__ __launch_bounds__(256) void k4(P p) {
    long t = (long)blockIdx.x * 256 + threadIdx.x;
    if (t >= (long)p.N * 16) return;
    int n = (int)(t >> 4), qq = (int)(t & 15);
    char st = p.stat[n];
    float coef = (st != 0) ? 1.0f : 0.0f;
    float4 hb4 = ((const float4*)(p.F + 128))[qq];
    float4 b24 = ((const float4*)p.b2)[qq];
    float4 o;
    o.x = b24.x + coef * hb4.x; o.y = b24.y + coef * hb4.y;
    o.z = b24.z + coef * hb4.z; o.w = b24.w + coef * hb4.w;
    if (st == 2) {
        float den = p.s_spec[n] + EPSF;
        float ad2v = p.adsp[n];
        float md = LRELU(p.F[192] + ad2v);
        int pos = p.map2[n];
        while (pos >= 0) {
            int sl = p.slw[pos];
            float w = expf(LRELU(p.as2tab[sl] + ad2v) - md) / den;
            float4 h4 = ((const float4*)(p.h2tab + sl * 64))[qq];
            o.x = fmaf(w, h4.x, o.x); o.y = fmaf(w, h4.y, o.y);
            o.z = fmaf(w, h4.z, o.z); o.w = fmaf(w, h4.w, o.w);
            pos = p.nxt[pos];
        }
    }
    p.out[t] = o;
}

extern "C" void kernel_launch(void* const* d_in, const int* in_sizes, int n_in,
                              void* d_out, int out_size, void* d_ws, size_t ws_size,
                              hipStream_t stream) {
    P p;
    p.x      = (const float*)d_in[0];
    p.EI     = (const int*)d_in[1];
    p.W1     = (const float*)d_in[2];
    p.a_src1 = (const float*)d_in[3];
    p.a_dst1 = (const float*)d_in[4];
    p.b1     = (const float*)d_in[5];
    p.W2     = (const float*)d_in[6];
    p.a_src2 = (const float*)d_in[7];
    p.a_dst2 = (const float*)d_in[8];
    p.b2     = (const float*)d_in[9];
    p.out    = (float4*)d_out;
    p.N = in_sizes[0] / 64;
    p.E = in_sizes[1] / 2;

    char* base = (char*)d_ws;
    p.F      = (float*)base;                          // 256 floats
    p.bcnt   = (int*)(base + 1024);                   // NB*16
    p.map2   = p.bcnt + NB * 16;                      // N
    p.s_spec = (float*)(p.map2 + p.N);                // N
    p.adsp   = p.s_spec + p.N;                        // N
    p.stat   = (char*)(p.adsp + p.N);                 // N bytes
    char* q  = p.stat + p.N;
    q = (char*)(((uintptr_t)q + 63) & ~(uintptr_t)63);
    p.pkey   = (int*)q;                               // 512
    p.as2tab = (float*)(p.pkey + 512);                // 512
    p.ad2tab = p.as2tab + 512;                        // 512
    p.h2tab  = p.ad2tab + 512;                        // 512*64
    p.slw    = (int*)(p.h2tab + 512 * 64);            // NB*BCAP
    p.nxt    = p.slw + NB * BCAP;                     // NB*BCAP

    p.initBlocks = (p.N + 255) / 256;                 // 391: init as parallel as R3

    long quads = ((long)p.E - 500 + 3) / 4;
    int scanBlocks = (int)((quads + 255) / 256);      // R3-proven geometry

    k1<<<p.initBlocks, 256, 0, stream>>>(p);
    k2<<<scanBlocks, 256, 0, stream>>>(p);
    k3<<<scanBlocks, 256, 0, stream>>>(p);
    k4<<<(int)(((long)p.N * 16 + 255) / 256), 256, 0, stream>>>(p);
}

// Round 8
// 61.570 us; speedup vs baseline: 10.5805x; 1.0578x over previous
//
#include <hip/hip_runtime.h>

// GAT encoder, MI355X — round 8: R3's proven 6-kernel skeleton with ONE delta:
// l1bc+l1d merged into l1k (owner-computes-segment, register-resident; validated
// in R6/R7). No LDS hash (R3's global idx_map lookups). 5 kernels, 4 gaps.
//  L1 (500 edges) -> <=500 special nodes (owner edges); all others x1 = b1.
//  L2: plain nodes share h2=hb. Softmax shift m=e_plain(d): plain weight = 1.
//  out[d] = b2 + coef*hb + sum_spec w*(h2-hb); den(d) = s_spec[d] =
//  (exp(esp-md)-1 per special edge, scanA) + (+1 per in-edge of special dst, scanB).

#define LRELU(v) ((v) >= 0.0f ? (v) : 0.2f * (v))
#define EPSF 1e-16f
#define NB 128
#define BCAP 512

struct P {
    const float* x; const int* EI; int E, N;
    const float *W1, *a_src1, *a_dst1, *b1, *W2, *a_src2, *a_dst2, *b2;
    float* F;        // F[128..191]=hb, F[192]=as_base, F[193]=ad_base
    int* bcnt;       // NB*16 padded bucket counters
    int* idx_map;    // N: special node -> owner edge id (slot), else -1
    int* map2;       // N: chain head per dst (-1)
    float* s_spec;   // N: denominator accumulator
    float* adsp;     // N: ad2 value of special dsts (written by scanA)
    char* stat;      // N: 0=no in-edge, 1=plain in-edge, 2=special dst
    float* as2tab; float* ad2tab; float* h2tab;   // slot = owner edge id (0..499)
    int* slw; int* nxt;                            // bucketed chain storage
    float4* out;
};

__device__ __forceinline__ float wred_sum(float v) {
    for (int o = 32; o; o >>= 1) v += __shfl_xor(v, o);
    return v;
}
__device__ __forceinline__ int wred_min(int v) {
    for (int o = 32; o; o >>= 1) v = min(v, __shfl_xor(v, o));
    return v;
}

// ---------------- initk: array init + F compute (R3-style) ----------------
__global__ __launch_bounds__(256) void initk(P p) {
    int i = blockIdx.x * 256 + threadIdx.x;
    if (i < p.N) { p.idx_map[i] = -1; p.map2[i] = -1; p.s_spec[i] = 0.f; p.stat[i] = 0; }
    if (i < NB * 16) p.bcnt[i] = 0;
    if (blockIdx.x == 0 && threadIdx.x < 64) {
        int t = threadIdx.x;
        float hb = 0.f;
        for (int k = 0; k < 64; ++k) hb += p.b1[k] * p.W2[k * 64 + t];
        p.F[128 + t] = hb;
        float as = wred_sum(hb * p.a_src2[t]);
        float ad = wred_sum(hb * p.a_dst2[t]);
        if (t == 0) { p.F[192] = as; p.F[193] = ad; }
    }
}

// ---------------- l1k: full layer 1, owner-computes-segment ----------------
__global__ __launch_bounds__(256) void l1k(P p) {
    const int w = (blockIdx.x * 256 + threadIdx.x) >> 6;
    const int lane = threadIdx.x & 63;
    if (w >= 500) return;

    // per-lane weight vectors (L2-hot recompute; no cross-wave deps)
    float wsl = 0.f, wdl = 0.f, hbl = 0.f;
    for (int l = 0; l < 64; ++l) {
        wsl += p.W1[lane * 64 + l] * p.a_src1[l];
        wdl += p.W1[lane * 64 + l] * p.a_dst1[l];
    }
    for (int k = 0; k < 64; ++k) hbl += p.b1[k] * p.W2[k * 64 + lane];

    const int d = p.EI[p.E + w];
    int firstj = 1 << 30;                 // owner = min edge index with this dst
    for (int r = 0; r < 8; ++r) {
        int j = r * 64 + lane;
        if (j < 500 && p.EI[p.E + j] == d) firstj = min(firstj, j);
    }
    firstj = wred_min(firstj);
    if (firstj != w) return;              // not the owner
    if (lane == 0) p.idx_map[d] = w;      // membership + slot for scanA/outk

    const float dv = wred_sum(p.x[(long)d * 64 + lane] * wdl);
    float Ssum = 0.f, e1w = 0.f, x1l = 0.f;
    bool fm = true;
    for (int r = 0; r < 8; ++r) {
        int j = r * 64 + lane;
        bool m = (j < 500) && (p.EI[p.E + j] == d);
        unsigned long long mask = __ballot(m);
        while (mask) {
            int j0 = r * 64 + (int)__ffsll(mask) - 1;
            mask &= mask - 1;
            int sj = p.EI[j0];
            float xs = p.x[(long)sj * 64 + lane];
            float e1j = LRELU(wred_sum(xs * wsl) + dv);
            float ew;
            if (fm) { e1w = e1j; ew = 1.f; fm = false; }   // shift anchor = own score
            else ew = expf(e1j - e1w);
            Ssum += ew;
            float h1l = 0.f;
            #pragma unroll
            for (int k = 0; k < 64; ++k) h1l = fmaf(__shfl(xs, k), p.W1[k * 64 + lane], h1l);
            x1l = fmaf(ew, h1l, x1l);
        }
    }
    float x1 = x1l / (Ssum + EPSF) + p.b1[lane];
    float h2l = 0.f;
    #pragma unroll
    for (int k = 0; k < 64; ++k) h2l = fmaf(__shfl(x1, k), p.W2[k * 64 + lane], h2l);
    p.h2tab[w * 64 + lane] = h2l - hbl;               // store (h2 - hb)
    float as = wred_sum(h2l * p.a_src2[lane]);
    float ad = wred_sum(h2l * p.a_dst2[lane]);
    if (lane == 0) { p.as2tab[w] = as; p.ad2tab[w] = ad; }
}

// ---------------- scanAk: src-column scan (R3 verbatim + adsp) ----------------
__device__ __forceinline__ void specEdge(const P& p, long e, int s, int bkt,
                                         float asb, float adb) {
    int sl = p.idx_map[s];
    if (sl < 0) return;
    int d = p.EI[p.E + e];
    int jd = p.idx_map[d];
    float ad2v = (jd >= 0) ? p.ad2tab[jd] : adb;
    float md  = LRELU(asb + ad2v);
    float esp = LRELU(p.as2tab[sl] + ad2v);
    atomicAdd(&p.s_spec[d], expf(esp - md) - 1.0f);
    p.stat[d] = 2;
    p.adsp[d] = ad2v;                                // same value from all writers
    int i = atomicAdd(&p.bcnt[bkt * 16], 1);         // 128 padded bucket counters
    if (i < BCAP) {
        int pos = bkt * BCAP + i;
        p.slw[pos] = sl;
        p.nxt[pos] = atomicExch(&p.map2[d], pos);
    }
}

__global__ __launch_bounds__(256) void scanAk(P p) {
    long q = (long)blockIdx.x * 256 + threadIdx.x;
    long base = 500 + q * 4;
    if (base >= p.E) return;
    const float asb = p.F[192], adb = p.F[193];
    int bkt = (int)(q & (NB - 1));
    if (base + 3 < p.E) {
        int4 s4 = *(const int4*)(p.EI + base);
        specEdge(p, base + 0, s4.x, bkt, asb, adb);
        specEdge(p, base + 1, s4.y, bkt, asb, adb);
        specEdge(p, base + 2, s4.z, bkt, asb, adb);
        specEdge(p, base + 3, s4.w, bkt, asb, adb);
    } else {
        for (long e = base; e < p.E; ++e) specEdge(p, e, p.EI[e], bkt, asb, adb);
    }
}

// ---------------- scanBk: dst-column scan (R3 verbatim) ----------------
__device__ __forceinline__ void dstEdge(const P& p, int d) {
    char st = p.stat[d];
    if (st == 0) p.stat[d] = 1;                      // benign race
    else if (st == 2) atomicAdd(&p.s_spec[d], 1.0f);
}

__global__ __launch_bounds__(256) void scanBk(P p) {
    long q = (long)blockIdx.x * 256 + threadIdx.x;
    long base = 500 + q * 4;
    if (base >= p.E) return;
    if (base + 3 < p.E) {
        int4 d4 = *(const int4*)(p.EI + p.E + base);
        dstEdge(p, d4.x); dstEdge(p, d4.y); dstEdge(p, d4.z); dstEdge(p, d4.w);
    } else {
        for (long e = base; e < p.E; ++e) dstEdge(p, p.EI[p.E + e]);
    }
}

// ---------------- outk: output writer (R3 verbatim, adsp instead of idx_map) ----
__global__ __launch_bounds__(256) void outk(P p) {
    long t = (long)blockIdx.x * 256 + threadIdx.x;
    if (t >= (long)p.N * 16) return;
    int n = (int)(t >> 4), qq = (int)(t & 15);
    char st = p.stat[n];
    float coef = (st != 0) ? 1.0f : 0.0f;
    float4 hb4 = ((const float4*)(p.F + 128))[qq];
    float4 b24 = ((const float4*)p.b2)[qq];
    float4 o;
    o.x = b24.x + coef * hb4.x; o.y = b24.y + coef * hb4.y;
    o.z = b24.z + coef * hb4.z; o.w = b24.w + coef * hb4.w;
    if (st == 2) {
        float den = p.s_spec[n] + EPSF;
        float ad2v = p.adsp[n];
        float md = LRELU(p.F[192] + ad2v);
        int pos = p.map2[n];
        while (pos >= 0) {
            int sl = p.slw[pos];
            float w = expf(LRELU(p.as2tab[sl] + ad2v) - md) / den;
            float4 h4 = ((const float4*)(p.h2tab + sl * 64))[qq];
            o.x = fmaf(w, h4.x, o.x); o.y = fmaf(w, h4.y, o.y);
            o.z = fmaf(w, h4.z, o.z); o.w = fmaf(w, h4.w, o.w);
            pos = p.nxt[pos];
        }
    }
    p.out[t] = o;
}

extern "C" void kernel_launch(void* const* d_in, const int* in_sizes, int n_in,
                              void* d_out, int out_size, void* d_ws, size_t ws_size,
                              hipStream_t stream) {
    P p;
    p.x      = (const float*)d_in[0];
    p.EI     = (const int*)d_in[1];
    p.W1     = (const float*)d_in[2];
    p.a_src1 = (const float*)d_in[3];
    p.a_dst1 = (const float*)d_in[4];
    p.b1     = (const float*)d_in[5];
    p.W2     = (const float*)d_in[6];
    p.a_src2 = (const float*)d_in[7];
    p.a_dst2 = (const float*)d_in[8];
    p.b2     = (const float*)d_in[9];
    p.out    = (float4*)d_out;
    p.N = in_sizes[0] / 64;
    p.E = in_sizes[1] / 2;

    char* base = (char*)d_ws;
    p.F       = (float*)base;                         // 256 floats
    p.bcnt    = (int*)(base + 1024);                  // NB*16
    p.idx_map = p.bcnt + NB * 16;                     // N
    p.map2    = p.idx_map + p.N;                      // N
    p.s_spec  = (float*)(p.map2 + p.N);               // N
    p.adsp    = p.s_spec + p.N;                       // N
    p.stat    = (char*)(p.adsp + p.N);                // N bytes
    char* q   = p.stat + p.N;
    q = (char*)(((uintptr_t)q + 63) & ~(uintptr_t)63);
    p.as2tab  = (float*)q;                            // 512
    p.ad2tab  = p.as2tab + 512;                       // 512
    p.h2tab   = p.ad2tab + 512;                       // 512*64
    p.slw     = (int*)(p.h2tab + 512 * 64);           // NB*BCAP
    p.nxt     = p.slw + NB * BCAP;                    // NB*BCAP

    long quads = ((long)p.E - 500 + 3) / 4;
    int scanBlocks = (int)((quads + 255) / 256);      // R3-proven geometry

    initk <<<(p.N + 255) / 256, 256, 0, stream>>>(p);
    l1k   <<<125, 256, 0, stream>>>(p);
    scanAk<<<scanBlocks, 256, 0, stream>>>(p);
    scanBk<<<scanBlocks, 256, 0, stream>>>(p);
    outk  <<<(int)(((long)p.N * 16 + 255) / 256), 256, 0, stream>>>(p);
}

// Round 9
// 59.206 us; speedup vs baseline: 11.0029x; 1.0399x over previous
//
#include <hip/hip_runtime.h>

// GAT encoder, MI355X — round 9: R8 skeleton + L1-resident bitmap membership.
//  L1 (500 edges) -> <=500 special nodes (owner edges); all others x1 = b1.
//  L2: plain nodes share h2=hb. Softmax shift m=e_plain(d): plain weight = 1.
//  out[d] = b2 + coef*hb + sum_spec w*(h2-hb); den(d) = s_spec[d] =
//  (exp(esp-md)-1 per special edge, scanA) + (+1 per in-edge of special dst, scanB).
//  scanA: srcbm bitmap test (12.5 KB, L1) ; scanB: blind flag store + dstbm test.

#define LRELU(v) ((v) >= 0.0f ? (v) : 0.2f * (v))
#define EPSF 1e-16f
#define NB 128
#define BCAP 512
#define BMW 3200   // bitmap words, covers N <= 102400

struct P {
    const float* x; const int* EI; int E, N;
    const float *W1, *a_src1, *a_dst1, *b1, *W2, *a_src2, *a_dst2, *b2;
    float* F;        // F[128..191]=hb, F[192]=as_base, F[193]=ad_base
    int* bcnt;       // NB*16 padded bucket counters
    int* idx_map;    // N: special node -> owner edge id (NO init; bitmap-guarded)
    int* map2;       // N: chain head per dst (-1)
    float* s_spec;   // N: denominator accumulator (init 0)
    float* adsp;     // N: ad2 of special dsts (NO init; bitmap-guarded)
    char* flag;      // N: has >=1 in-edge (init 0)
    unsigned* srcbm; // BMW: special-node bitmap (set by l1k)
    unsigned* dstbm; // BMW: special-dst bitmap (set by scanA)
    float* as2tab; float* ad2tab; float* h2tab;   // slot = owner edge id (0..499)
    int* slw; int* nxt;                            // bucketed chain storage
    float4* out;
};

__device__ __forceinline__ float wred_sum(float v) {
    for (int o = 32; o; o >>= 1) v += __shfl_xor(v, o);
    return v;
}
__device__ __forceinline__ int wred_min(int v) {
    for (int o = 32; o; o >>= 1) v = min(v, __shfl_xor(v, o));
    return v;
}
__device__ __forceinline__ bool bittest(const unsigned* bm, int n) {
    return (bm[n >> 5] >> (n & 31)) & 1u;
}

// ---------------- initk: array init + F compute ----------------
__global__ __launch_bounds__(256) void initk(P p) {
    int i = blockIdx.x * 256 + threadIdx.x;
    if (i < p.N) { p.map2[i] = -1; p.s_spec[i] = 0.f; p.flag[i] = 0; }
    if (i < BMW) { p.srcbm[i] = 0u; p.dstbm[i] = 0u; }
    if (i < NB * 16) p.bcnt[i] = 0;
    if (blockIdx.x == 0 && threadIdx.x < 64) {
        int t = threadIdx.x;
        float hb = 0.f;
        for (int k = 0; k < 64; ++k) hb += p.b1[k] * p.W2[k * 64 + t];
        p.F[128 + t] = hb;
        float as = wred_sum(hb * p.a_src2[t]);
        float ad = wred_sum(hb * p.a_dst2[t]);
        if (t == 0) { p.F[192] = as; p.F[193] = ad; }
    }
}

// ---------------- l1k: full layer 1, owner-computes-segment ----------------
__global__ __launch_bounds__(256) void l1k(P p) {
    const int w = (blockIdx.x * 256 + threadIdx.x) >> 6;
    const int lane = threadIdx.x & 63;
    if (w >= 500) return;

    // per-lane weight vectors: W1 row per lane, float4 (L2-hot)
    const float4* W1r = (const float4*)(p.W1 + lane * 64);
    const float4* as1 = (const float4*)p.a_src1;
    const float4* ad1 = (const float4*)p.a_dst1;
    float wsl = 0.f, wdl = 0.f;
    #pragma unroll
    for (int l = 0; l < 16; ++l) {
        float4 wv = W1r[l], av = as1[l], bv = ad1[l];
        wsl += wv.x * av.x + wv.y * av.y + wv.z * av.z + wv.w * av.w;
        wdl += wv.x * bv.x + wv.y * bv.y + wv.z * bv.z + wv.w * bv.w;
    }
    const float hbl = p.F[128 + lane];   // computed by initk

    const int d = p.EI[p.E + w];
    int firstj = 1 << 30;                 // owner = min edge index with this dst
    for (int r = 0; r < 8; ++r) {
        int j = r * 64 + lane;
        if (j < 500 && p.EI[p.E + j] == d) firstj = min(firstj, j);
    }
    firstj = wred_min(firstj);
    if (firstj != w) return;              // not the owner
    if (lane == 0) {
        p.idx_map[d] = w;                 // slot (bitmap-guarded read later)
        atomicOr(&p.srcbm[d >> 5], 1u << (d & 31));
    }

    const float dv = wred_sum(p.x[(long)d * 64 + lane] * wdl);
    float Ssum = 0.f, e1w = 0.f, x1l = 0.f;
    bool fm = true;
    for (int r = 0; r < 8; ++r) {
        int j = r * 64 + lane;
        bool m = (j < 500) && (p.EI[p.E + j] == d);
        unsigned long long mask = __ballot(m);
        while (mask) {
            int j0 = r * 64 + (int)__ffsll(mask) - 1;
            mask &= mask - 1;
            int sj = p.EI[j0];
            float xs = p.x[(long)sj * 64 + lane];
            float e1j = LRELU(wred_sum(xs * wsl) + dv);
            float ew;
            if (fm) { e1w = e1j; ew = 1.f; fm = false; }   // shift anchor = own score
            else ew = expf(e1j - e1w);
            Ssum += ew;
            float h1l = 0.f;
            #pragma unroll
            for (int k = 0; k < 64; ++k) h1l = fmaf(__shfl(xs, k), p.W1[k * 64 + lane], h1l);
            x1l = fmaf(ew, h1l, x1l);
        }
    }
    float x1 = x1l / (Ssum + EPSF) + p.b1[lane];
    float h2l = 0.f;
    #pragma unroll
    for (int k = 0; k < 64; ++k) h2l = fmaf(__shfl(x1, k), p.W2[k * 64 + lane], h2l);
    p.h2tab[w * 64 + lane] = h2l - hbl;               // store (h2 - hb)
    float as = wred_sum(h2l * p.a_src2[lane]);
    float ad = wred_sum(h2l * p.a_dst2[lane]);
    if (lane == 0) { p.as2tab[w] = as; p.ad2tab[w] = ad; }
}

// ---------------- scanAk: src-column scan (bitmap membership) ----------------
__device__ __forceinline__ void specEdge(const P& p, long e, int s, int bkt,
                                         float asb, float adb) {
    if (!bittest(p.srcbm, s)) return;                // L1-resident test
    int sl = p.idx_map[s];                           // rare (~8K)
    int d = p.EI[p.E + e];
    float ad2v = bittest(p.srcbm, d) ? p.ad2tab[p.idx_map[d]] : adb;
    float md  = LRELU(asb + ad2v);
    float esp = LRELU(p.as2tab[sl] + ad2v);
    atomicAdd(&p.s_spec[d], expf(esp - md) - 1.0f);
    p.adsp[d] = ad2v;                                // same value from all writers
    atomicOr(&p.dstbm[d >> 5], 1u << (d & 31));
    int i = atomicAdd(&p.bcnt[bkt * 16], 1);         // 128 padded bucket counters
    if (i < BCAP) {
        int pos = bkt * BCAP + i;
        p.slw[pos] = sl;
        p.nxt[pos] = atomicExch(&p.map2[d], pos);
    }
}

__global__ __launch_bounds__(256) void scanAk(P p) {
    long q = (long)blockIdx.x * 256 + threadIdx.x;
    long base = 500 + q * 4;
    if (base >= p.E) return;
    const float asb = p.F[192], adb = p.F[193];
    int bkt = (int)(q & (NB - 1));
    if (base + 3 < p.E) {
        int4 s4 = *(const int4*)(p.EI + base);
        specEdge(p, base + 0, s4.x, bkt, asb, adb);
        specEdge(p, base + 1, s4.y, bkt, asb, adb);
        specEdge(p, base + 2, s4.z, bkt, asb, adb);
        specEdge(p, base + 3, s4.w, bkt, asb, adb);
    } else {
        for (long e = base; e < p.E; ++e) specEdge(p, e, p.EI[e], bkt, asb, adb);
    }
}

// ---------------- scanBk: dst-column scan (read-free fast path) ----------------
__device__ __forceinline__ void dstEdge(const P& p, int d) {
    p.flag[d] = 1;                                   // blind store, benign race
    if (bittest(p.dstbm, d)) atomicAdd(&p.s_spec[d], 1.0f);
}

__global__ __launch_bounds__(256) void scanBk(P p) {
    long q = (long)blockIdx.x * 256 + threadIdx.x;
    long base = 500 + q * 4;
    if (base >= p.E) return;
    if (base + 3 < p.E) {
        int4 d4 = *(const int4*)(p.EI + p.E + base);
        dstEdge(p, d4.x); dstEdge(p, d4.y); dstEdge(p, d4.z); dstEdge(p, d4.w);
    } else {
        for (long e = base; e < p.E; ++e) dstEdge(p, p.EI[p.E + e]);
    }
}

// ---------------- outk: output writer ----------------
__global__ __launch_bounds__(256) void outk(P p) {
    long t = (long)blockIdx.x * 256 + threadIdx.x;
    if (t >= (long)p.N * 16) return;
    int n = (int)(t >> 4), qq = (int)(t & 15);
    float coef = p.flag[n] ? 1.0f : 0.0f;
    float4 hb4 = ((const float4*)(p.F + 128))[qq];
    float4 b24 = ((const float4*)p.b2)[qq];
    float4 o;
    o.x = b24.x + coef * hb4.x; o.y = b24.y + coef * hb4.y;
    o.z = b24.z + coef * hb4.z; o.w = b24.w + coef * hb4.w;
    if (bittest(p.dstbm, n)) {
        float den = p.s_spec[n] + EPSF;
        float ad2v = p.adsp[n];
        float md = LRELU(p.F[192] + ad2v);
        int pos = p.map2[n];
        while (pos >= 0) {
            int sl = p.slw[pos];
            float w = expf(LRELU(p.as2tab[sl] + ad2v) - md) / den;
            float4 h4 = ((const float4*)(p.h2tab + sl * 64))[qq];
            o.x = fmaf(w, h4.x, o.x); o.y = fmaf(w, h4.y, o.y);
            o.z = fmaf(w, h4.z, o.z); o.w = fmaf(w, h4.w, o.w);
            pos = p.nxt[pos];
        }
    }
    p.out[t] = o;
}

extern "C" void kernel_launch(void* const* d_in, const int* in_sizes, int n_in,
                              void* d_out, int out_size, void* d_ws, size_t ws_size,
                              hipStream_t stream) {
    P p;
    p.x      = (const float*)d_in[0];
    p.EI     = (const int*)d_in[1];
    p.W1     = (const float*)d_in[2];
    p.a_src1 = (const float*)d_in[3];
    p.a_dst1 = (const float*)d_in[4];
    p.b1     = (const float*)d_in[5];
    p.W2     = (const float*)d_in[6];
    p.a_src2 = (const float*)d_in[7];
    p.a_dst2 = (const float*)d_in[8];
    p.b2     = (const float*)d_in[9];
    p.out    = (float4*)d_out;
    p.N = in_sizes[0] / 64;
    p.E = in_sizes[1] / 2;

    char* base = (char*)d_ws;
    p.F       = (float*)base;                         // 256 floats
    p.bcnt    = (int*)(base + 1024);                  // NB*16
    p.idx_map = p.bcnt + NB * 16;                     // N (uninit)
    p.map2    = p.idx_map + p.N;                      // N
    p.s_spec  = (float*)(p.map2 + p.N);               // N
    p.adsp    = p.s_spec + p.N;                       // N (uninit)
    p.flag    = (char*)(p.adsp + p.N);                // N bytes
    char* q   = p.flag + p.N;
    q = (char*)(((uintptr_t)q + 63) & ~(uintptr_t)63);
    p.srcbm   = (unsigned*)q;                         // BMW
    p.dstbm   = p.srcbm + BMW;                        // BMW
    p.as2tab  = (float*)(p.dstbm + BMW);              // 512
    p.ad2tab  = p.as2tab + 512;                       // 512
    p.h2tab   = p.ad2tab + 512;                       // 512*64
    p.slw     = (int*)(p.h2tab + 512 * 64);           // NB*BCAP
    p.nxt     = p.slw + NB * BCAP;                    // NB*BCAP

    long quads = ((long)p.E - 500 + 3) / 4;
    int scanBlocks = (int)((quads + 255) / 256);

    initk <<<(p.N + 255) / 256, 256, 0, stream>>>(p);
    l1k   <<<125, 256, 0, stream>>>(p);
    scanAk<<<scanBlocks, 256, 0, stream>>>(p);
    scanBk<<<scanBlocks, 256, 0, stream>>>(p);
    outk  <<<(int)(((long)p.N * 16 + 255) / 256), 256, 0, stream>>>(p);
}